// Round 4
// baseline (186.146 us; speedup 1.0000x reference)
//
#include <hip/hip_runtime.h>
#include <cstdint>

// y = clip(round((x @ W^T) * (sx*sw/sy)), -128, 127), M=8192 N=4096 K=4096 int8.
// Pass 1 (pack): int32 -> int8, permuted to MFMA-fragment-major, kh-major halves:
//   per (256-row block, 128B K-tile): 32KB = [kh 0/1][rf 0..15][lane*16],
//   lane = kl*16+fr holds rows rf*16+fr, K-bytes kt*128 + kh*64 + kl*16..+15
//   (exact mfma_i32_16x16x64_i8 operand order). Each 16KB half is contiguous.
// Pass 2 (GEMM): 256x256 tile, 8 waves (2Mx4N), ring-2 LDS (128KB), 4-phase
//   schedule per K-tile (T3+T4): per phase {ds_read frags, issue 1 half-tile
//   stage, barrier, setprio(1), 16 MFMA, setprio(0), [vmcnt(4)], barrier}.
//   vmcnt counted (4 loads always in flight), never drained mid-loop.

#define MDIM 8192
#define NDIM 4096
#define KDIM 4096
#define BM 256
#define BN 256
#define BKB 128
#define NT (KDIM / BKB)  // 32 K-tiles

typedef int v4i __attribute__((ext_vector_type(4)));

#define FENCE() asm volatile("" ::: "memory")
#define BAR()                     \
  do {                            \
    FENCE();                      \
    __builtin_amdgcn_s_barrier(); \
    FENCE();                      \
  } while (0)

__device__ __forceinline__ uint32_t pack4(int a, int b, int c, int d) {
  return (uint32_t)(a & 0xFF) | ((uint32_t)(b & 0xFF) << 8) |
         ((uint32_t)(c & 0xFF) << 16) | ((uint32_t)(d & 0xFF) << 24);
}

// ---------- pack: gather int32 -> fragment-major int8 + scale_y tail ----------
__global__ __launch_bounds__(256) void pack_kernel(
    const int* __restrict__ x32, const int* __restrict__ w32,
    const float* __restrict__ sy, uint8_t* __restrict__ x8f,
    uint8_t* __restrict__ w8f, float* __restrict__ tail) {
  const int t = blockIdx.x * 256 + threadIdx.x;
  if (t < NDIM) tail[t] = sy[t];
  const int NXC = (MDIM / 16) * KDIM;  // 2,097,152 16B-chunks for x
  const int NWC = (NDIM / 16) * KDIM;  // 1,048,576 for w
  if (t >= NXC + NWC) return;
  const int* src;
  uint8_t* dst;
  int chunk;
  if (t < NXC) {
    chunk = t;
    src = x32;
    dst = x8f;
  } else {
    chunk = t - NXC;
    src = w32;
    dst = w8f;
  }
  const int blk = chunk >> 11;  // 2048 chunks per 32KB tile-block
  const int cb = chunk & 2047;
  const int mb = blk >> 5;  // 256-row block
  const int kt = blk & 31;  // 128B K-tile
  const int region = cb >> 6;
  const int lpos = cb & 63;
  const int kh = region >> 4, rf = region & 15;  // kh-major halves
  const int kl = lpos >> 4, fr = lpos & 15;
  const int r = mb * 256 + rf * 16 + fr;
  const int k0 = kt * 128 + kh * 64 + kl * 16;
  const int* s = src + (size_t)r * KDIM + k0;  // 16 int32 = 64B aligned line
  v4i a0 = *(const v4i*)(s + 0);
  v4i a1 = *(const v4i*)(s + 4);
  v4i a2 = *(const v4i*)(s + 8);
  v4i a3 = *(const v4i*)(s + 12);
  v4i o;
  o[0] = (int)pack4(a0[0], a0[1], a0[2], a0[3]);
  o[1] = (int)pack4(a1[0], a1[1], a1[2], a1[3]);
  o[2] = (int)pack4(a2[0], a2[1], a2[2], a2[3]);
  o[3] = (int)pack4(a3[0], a3[1], a3[2], a3[3]);
  *(v4i*)(dst + (size_t)chunk * 16) = o;  // linear, fully coalesced
}

// ---------- main GEMM ----------------------------------------------------------
// 512 threads = 8 waves (2M x 4N), per-wave output 128x64, acc 8x4 frags.
// LDS: [buf 0/1][A 32KB][B 32KB] = 128KB.
// Phase plan per K-tile t (halves of tile t+1 staged one per phase):
//   p0: read af(kh0,i0..3)+bf(kh0); stage A-h0(t+1); BAR; MFMA16;            BAR
//   p1: read af(kh0,i4..7);         stage B-h0(t+1); BAR; MFMA16; vmcnt(4);  BAR
//   p2: read af(kh1,i0..3)+bf(kh1); stage A-h1(t+1); BAR; MFMA16;            BAR
//   p3: read af(kh1,i4..7);         stage B-h1(t+1); BAR; MFMA16; vmcnt(4);  BAR
// Invariant at p1-wait: oldest-4 = A-h1,B-h1 of tile t (needed p2/p3) done,
// 4 of tile t+1 in flight. At p3-wait: A-h0,B-h0 of t+1 (needed next p0) done.
__global__ __launch_bounds__(512, 2) void gemm_kernel(
    const uint8_t* __restrict__ A8, const uint8_t* __restrict__ B8,
    const float* __restrict__ sxp, const float* __restrict__ swp,
    const float* __restrict__ syp, float* __restrict__ out) {
  __shared__ __align__(16) uint8_t lds[131072];

  const int tid = threadIdx.x;
  const int lane = tid & 63;
  const int wave = tid >> 6;

  // XCD-aware swizzle: nwg = 512 (divisible by 8 -> bijective)
  const int wg = ((int)blockIdx.x % 8) * 64 + (int)blockIdx.x / 8;
  const int mb = wg >> 4;  // 0..31
  const int nb = wg & 15;  // 0..15

  const int wm2 = wave >> 2;  // 0..1
  const int wn4 = wave & 3;   // 0..3

  const uint8_t* Abase = A8 + ((size_t)(mb * 32) << 15);
  const uint8_t* Bbase = B8 + ((size_t)(nb * 32) << 15);

  const uint32_t sdst = (uint32_t)tid * 16;
  const uint32_t lane16 = (uint32_t)lane * 16;
  const uint32_t aoff = (uint32_t)(wm2 * 8) << 10;
  const uint32_t boff = (uint32_t)(wn4 * 4) << 10;

  v4i acc[8][4];
#pragma unroll
  for (int i = 0; i < 8; i++)
#pragma unroll
    for (int j = 0; j < 4; j++) acc[i][j] = (v4i){0, 0, 0, 0};

  auto gload = [&](const uint8_t* src, uint32_t ldsoff) {
    __builtin_amdgcn_global_load_lds(
        (const __attribute__((address_space(1))) void*)src,
        (__attribute__((address_space(3))) void*)(lds + ldsoff), 16, 0, 0);
  };
  auto stageA = [&](int t, int kh) {  // 16KB half: 2 loads/thread
    const uint32_t lb = (uint32_t)(t & 1) * 65536u + (uint32_t)kh * 16384u + sdst;
    const uint8_t* s = Abase + ((size_t)t << 15) + (uint32_t)(kh * 16384) + sdst;
    gload(s, lb);
    gload(s + 8192, lb + 8192);
  };
  auto stageB = [&](int t, int kh) {
    const uint32_t lb =
        (uint32_t)(t & 1) * 65536u + 32768u + (uint32_t)kh * 16384u + sdst;
    const uint8_t* s = Bbase + ((size_t)t << 15) + (uint32_t)(kh * 16384) + sdst;
    gload(s, lb);
    gload(s + 8192, lb + 8192);
  };

  // prologue: tile 0, halves in order A0,B0,A1,B1 (8 loads)
  stageA(0, 0);
  stageB(0, 0);
  stageA(0, 1);
  stageB(0, 1);
  asm volatile("s_waitcnt vmcnt(4)" ::: "memory");  // A-h0,B-h0 landed
  BAR();

  for (int t = 0; t < NT; ++t) {
    const uint8_t* LA = lds + (uint32_t)(t & 1) * 65536u;
    const uint8_t* LB = LA + 32768u;
    const bool pre = (t + 1 < NT);
    v4i af[4], bf[4];

    // ---- phase 0: kh=0, i=0..3 ----
#pragma unroll
    for (int i = 0; i < 4; i++)
      af[i] = *(const v4i*)(LA + aoff + (i << 10) + lane16);
#pragma unroll
    for (int j = 0; j < 4; j++)
      bf[j] = *(const v4i*)(LB + boff + (j << 10) + lane16);
    if (pre) stageA(t + 1, 0);
    BAR();
    __builtin_amdgcn_s_setprio(1);
#pragma unroll
    for (int i = 0; i < 4; i++)
#pragma unroll
      for (int j = 0; j < 4; j++)
        acc[i][j] =
            __builtin_amdgcn_mfma_i32_16x16x64_i8(af[i], bf[j], acc[i][j], 0, 0, 0);
    __builtin_amdgcn_s_setprio(0);
    BAR();

    // ---- phase 1: kh=0, i=4..7 (bf reused) ----
#pragma unroll
    for (int i = 0; i < 4; i++)
      af[i] = *(const v4i*)(LA + aoff + ((4 + i) << 10) + lane16);
    if (pre) stageB(t + 1, 0);
    BAR();
    __builtin_amdgcn_s_setprio(1);
#pragma unroll
    for (int i = 0; i < 4; i++)
#pragma unroll
      for (int j = 0; j < 4; j++)
        acc[4 + i][j] =
            __builtin_amdgcn_mfma_i32_16x16x64_i8(af[i], bf[j], acc[4 + i][j], 0, 0, 0);
    __builtin_amdgcn_s_setprio(0);
    if (pre)
      asm volatile("s_waitcnt vmcnt(4)" ::: "memory");  // t's kh1 halves landed
    else
      asm volatile("s_waitcnt vmcnt(0)" ::: "memory");
    BAR();

    // ---- phase 2: kh=1, i=0..3 ----
#pragma unroll
    for (int i = 0; i < 4; i++)
      af[i] = *(const v4i*)(LA + 16384u + aoff + (i << 10) + lane16);
#pragma unroll
    for (int j = 0; j < 4; j++)
      bf[j] = *(const v4i*)(LB + 16384u + boff + (j << 10) + lane16);
    if (pre) stageA(t + 1, 1);
    BAR();
    __builtin_amdgcn_s_setprio(1);
#pragma unroll
    for (int i = 0; i < 4; i++)
#pragma unroll
      for (int j = 0; j < 4; j++)
        acc[i][j] =
            __builtin_amdgcn_mfma_i32_16x16x64_i8(af[i], bf[j], acc[i][j], 0, 0, 0);
    __builtin_amdgcn_s_setprio(0);
    BAR();

    // ---- phase 3: kh=1, i=4..7 ----
#pragma unroll
    for (int i = 0; i < 4; i++)
      af[i] = *(const v4i*)(LA + 16384u + aoff + ((4 + i) << 10) + lane16);
    if (pre) stageB(t + 1, 1);
    BAR();
    __builtin_amdgcn_s_setprio(1);
#pragma unroll
    for (int i = 0; i < 4; i++)
#pragma unroll
      for (int j = 0; j < 4; j++)
        acc[4 + i][j] =
            __builtin_amdgcn_mfma_i32_16x16x64_i8(af[i], bf[j], acc[4 + i][j], 0, 0, 0);
    __builtin_amdgcn_s_setprio(0);
    if (pre)
      asm volatile("s_waitcnt vmcnt(4)" ::: "memory");  // t+1's kh0 halves landed
    BAR();
  }

  // epilogue: requantize, round-half-even, clip, store float
  const float s = sxp[0] * swp[0];
  const int kl = lane >> 4;
  const int fr = lane & 15;
  const int wrow = mb * 256 + wm2 * 128;
  const int wcol = nb * 256 + wn4 * 64;
#pragma unroll
  for (int j = 0; j < 4; j++) {
    const int col = wcol + j * 16 + fr;
    const float rs = s / syp[col];
#pragma unroll
    for (int i = 0; i < 8; i++) {
      const int row0 = wrow + i * 16 + kl * 4;
#pragma unroll
      for (int r = 0; r < 4; r++) {
        float v = rintf((float)acc[i][j][r] * rs);
        v = fminf(127.f, fmaxf(-128.f, v));
        out[(size_t)(row0 + r) * NDIM + col] = v;
      }
    }
  }
}

extern "C" void kernel_launch(void* const* d_in, const int* in_sizes, int n_in,
                              void* d_out, int out_size, void* d_ws, size_t ws_size,
                              hipStream_t stream) {
  const int* x32 = (const int*)d_in[0];
  const int* w32 = (const int*)d_in[1];
  const float* sx = (const float*)d_in[2];
  const float* sw = (const float*)d_in[3];
  const float* sy = (const float*)d_in[4];
  float* out = (float*)d_out;
  float* tail = out + (size_t)MDIM * NDIM;

  uint8_t* x8f = (uint8_t*)d_ws;
  uint8_t* w8f = x8f + (size_t)MDIM * KDIM;

  const int total = (MDIM / 16) * KDIM + (NDIM / 16) * KDIM;  // 3,145,728
  pack_kernel<<<total / 256, 256, 0, stream>>>(x32, w32, sy, x8f, w8f, tail);

  const int nblocks = (MDIM / BM) * (NDIM / BN);  // 512
  gemm_kernel<<<nblocks, 512, 0, stream>>>(x8f, w8f, sx, sw, sy, out);
}

// Round 5
// 185.811 us; speedup vs baseline: 1.0018x; 1.0018x over previous
//
#include <hip/hip_runtime.h>
#include <cstdint>

// y = clip(round((x @ W^T) * (sx*sw/sy)), -128, 127), M=8192 N=4096 K=4096 int8.
// Pass 1 (pack): int32 -> int8, permuted to MFMA-fragment-major, kh-major halves:
//   per (256-row block, 128B K-tile): 32KB = [kh 0/1][rf 0..15][lane*16],
//   lane = kl*16+fr holds rows rf*16+fr, K-bytes kt*128 + kh*64 + kl*16..+15
//   (exact mfma_i32_16x16x64_i8 operand order). Conflict-free ds_read_b128
//   (region + lane*16, stride-1) -- verified SQ_LDS_BANK_CONFLICT = 0.
// Pass 2 (GEMM): 256x256 tile, 8 waves (2Mx4N), ring-2 LDS (128KB), ONE barrier
//   per K-tile: {vmcnt(0); BAR; stage(t+1); 24 ds_read_b128; 64 MFMA}.
//   Loads for t+1 issue right after BAR and have the whole tile body
//   (~2600 cyc) to land before the next top-of-loop drain (>HBM 900 cyc).
//   Single basic block lets the compiler pipeline ds_reads under MFMAs
//   (fine-grained lgkmcnt) and waves drift within the tile -> LDS/MFMA overlap.

#define MDIM 8192
#define NDIM 4096
#define KDIM 4096
#define BM 256
#define BN 256
#define BKB 128
#define NT (KDIM / BKB)  // 32 K-tiles

typedef int v4i __attribute__((ext_vector_type(4)));

#define FENCE() asm volatile("" ::: "memory")
#define BAR()                     \
  do {                            \
    FENCE();                      \
    __builtin_amdgcn_s_barrier(); \
    FENCE();                      \
  } while (0)

__device__ __forceinline__ uint32_t pack4(int a, int b, int c, int d) {
  return (uint32_t)(a & 0xFF) | ((uint32_t)(b & 0xFF) << 8) |
         ((uint32_t)(c & 0xFF) << 16) | ((uint32_t)(d & 0xFF) << 24);
}

// ---------- pack: gather int32 -> fragment-major int8 + scale_y tail ----------
__global__ __launch_bounds__(256) void pack_kernel(
    const int* __restrict__ x32, const int* __restrict__ w32,
    const float* __restrict__ sy, uint8_t* __restrict__ x8f,
    uint8_t* __restrict__ w8f, float* __restrict__ tail) {
  const int t = blockIdx.x * 256 + threadIdx.x;
  if (t < NDIM) tail[t] = sy[t];
  const int NXC = (MDIM / 16) * KDIM;  // 2,097,152 16B-chunks for x
  const int NWC = (NDIM / 16) * KDIM;  // 1,048,576 for w
  if (t >= NXC + NWC) return;
  const int* src;
  uint8_t* dst;
  int chunk;
  if (t < NXC) {
    chunk = t;
    src = x32;
    dst = x8f;
  } else {
    chunk = t - NXC;
    src = w32;
    dst = w8f;
  }
  const int blk = chunk >> 11;  // 2048 chunks per 32KB tile-block
  const int cb = chunk & 2047;
  const int mb = blk >> 5;  // 256-row block
  const int kt = blk & 31;  // 128B K-tile
  const int region = cb >> 6;
  const int lpos = cb & 63;
  const int kh = region >> 4, rf = region & 15;  // kh-major halves
  const int kl = lpos >> 4, fr = lpos & 15;
  const int r = mb * 256 + rf * 16 + fr;
  const int k0 = kt * 128 + kh * 64 + kl * 16;
  const int* s = src + (size_t)r * KDIM + k0;  // 16 int32 = 64B aligned line
  v4i a0 = *(const v4i*)(s + 0);
  v4i a1 = *(const v4i*)(s + 4);
  v4i a2 = *(const v4i*)(s + 8);
  v4i a3 = *(const v4i*)(s + 12);
  v4i o;
  o[0] = (int)pack4(a0[0], a0[1], a0[2], a0[3]);
  o[1] = (int)pack4(a1[0], a1[1], a1[2], a1[3]);
  o[2] = (int)pack4(a2[0], a2[1], a2[2], a2[3]);
  o[3] = (int)pack4(a3[0], a3[1], a3[2], a3[3]);
  *(v4i*)(dst + (size_t)chunk * 16) = o;  // linear, fully coalesced
}

// ---------- main GEMM ----------------------------------------------------------
// 512 threads = 8 waves (2M x 4N), per-wave output 128x64, acc 8x4 frags.
// LDS: [buf 0/1][A 32KB][B 32KB] = 128KB.
__global__ __launch_bounds__(512, 2) void gemm_kernel(
    const uint8_t* __restrict__ A8, const uint8_t* __restrict__ B8,
    const float* __restrict__ sxp, const float* __restrict__ swp,
    const float* __restrict__ syp, float* __restrict__ out) {
  __shared__ __align__(16) uint8_t lds[131072];

  const int tid = threadIdx.x;
  const int lane = tid & 63;
  const int wave = tid >> 6;

  // XCD-aware swizzle: nwg = 512 (divisible by 8 -> bijective)
  const int wg = ((int)blockIdx.x % 8) * 64 + (int)blockIdx.x / 8;
  const int mb = wg >> 4;  // 0..31
  const int nb = wg & 15;  // 0..15

  const int wm2 = wave >> 2;  // 0..1
  const int wn4 = wave & 3;   // 0..3

  const uint8_t* Abase = A8 + ((size_t)(mb * 32) << 15);
  const uint8_t* Bbase = B8 + ((size_t)(nb * 32) << 15);

  const uint32_t sdst = (uint32_t)tid * 16;
  const uint32_t lane16 = (uint32_t)lane * 16;
  const uint32_t aoff = (uint32_t)(wm2 * 8) << 10;
  const uint32_t boff = (uint32_t)(wn4 * 4) << 10;

  v4i acc[8][4];
#pragma unroll
  for (int i = 0; i < 8; i++)
#pragma unroll
    for (int j = 0; j < 4; j++) acc[i][j] = (v4i){0, 0, 0, 0};

  auto gload = [&](const uint8_t* src, uint32_t ldsoff) {
    __builtin_amdgcn_global_load_lds(
        (const __attribute__((address_space(1))) void*)src,
        (__attribute__((address_space(3))) void*)(lds + ldsoff), 16, 0, 0);
  };
  auto stage = [&](int t) {  // full 64KB tile: 8 loads/thread
    const uint32_t lb = (uint32_t)(t & 1) * 65536u + sdst;
    const uint8_t* sa = Abase + ((size_t)t << 15) + sdst;
    const uint8_t* sb = Bbase + ((size_t)t << 15) + sdst;
#pragma unroll
    for (int r = 0; r < 4; ++r) {
      gload(sa + r * 8192, lb + r * 8192);
      gload(sb + r * 8192, lb + 32768u + r * 8192);
    }
  };

  stage(0);  // 8 loads in flight

  for (int t = 0; t < NT; ++t) {
    // drain own loads (issued a full tile body ago), then sync all waves
    asm volatile("s_waitcnt vmcnt(0)" ::: "memory");
    BAR();
    // prefetch next tile into the other ring buffer; safe: all reads of
    // buf[(t+1)&1] (tile t-1) completed before any wave passed BAR above.
    if (t + 1 < NT) stage(t + 1);

    const uint8_t* LA = lds + (uint32_t)(t & 1) * 65536u;
    const uint8_t* LB = LA + 32768u;

    // all 24 fragment reads up front; compiler pipelines lgkmcnt under MFMAs
    v4i af0[8], bf0[4], af1[8], bf1[4];
#pragma unroll
    for (int j = 0; j < 4; j++)
      bf0[j] = *(const v4i*)(LB + boff + (j << 10) + lane16);
#pragma unroll
    for (int i = 0; i < 8; i++)
      af0[i] = *(const v4i*)(LA + aoff + (i << 10) + lane16);
#pragma unroll
    for (int j = 0; j < 4; j++)
      bf1[j] = *(const v4i*)(LB + 16384u + boff + (j << 10) + lane16);
#pragma unroll
    for (int i = 0; i < 8; i++)
      af1[i] = *(const v4i*)(LA + 16384u + aoff + (i << 10) + lane16);

#pragma unroll
    for (int i = 0; i < 8; i++)
#pragma unroll
      for (int j = 0; j < 4; j++)
        acc[i][j] =
            __builtin_amdgcn_mfma_i32_16x16x64_i8(af0[i], bf0[j], acc[i][j], 0, 0, 0);
#pragma unroll
    for (int i = 0; i < 8; i++)
#pragma unroll
      for (int j = 0; j < 4; j++)
        acc[i][j] =
            __builtin_amdgcn_mfma_i32_16x16x64_i8(af1[i], bf1[j], acc[i][j], 0, 0, 0);
  }

  // epilogue: requantize, round-half-even, clip, store float
  const float s = sxp[0] * swp[0];
  const int kl = lane >> 4;
  const int fr = lane & 15;
  const int wrow = mb * 256 + wm2 * 128;
  const int wcol = nb * 256 + wn4 * 64;
#pragma unroll
  for (int j = 0; j < 4; j++) {
    const int col = wcol + j * 16 + fr;
    const float rs = s / syp[col];
#pragma unroll
    for (int i = 0; i < 8; i++) {
      const int row0 = wrow + i * 16 + kl * 4;
#pragma unroll
      for (int r = 0; r < 4; r++) {
        float v = rintf((float)acc[i][j][r] * rs);
        v = fminf(127.f, fmaxf(-128.f, v));
        out[(size_t)(row0 + r) * NDIM + col] = v;
      }
    }
  }
}

extern "C" void kernel_launch(void* const* d_in, const int* in_sizes, int n_in,
                              void* d_out, int out_size, void* d_ws, size_t ws_size,
                              hipStream_t stream) {
  const int* x32 = (const int*)d_in[0];
  const int* w32 = (const int*)d_in[1];
  const float* sx = (const float*)d_in[2];
  const float* sw = (const float*)d_in[3];
  const float* sy = (const float*)d_in[4];
  float* out = (float*)d_out;
  float* tail = out + (size_t)MDIM * NDIM;

  uint8_t* x8f = (uint8_t*)d_ws;
  uint8_t* w8f = x8f + (size_t)MDIM * KDIM;

  const int total = (MDIM / 16) * KDIM + (NDIM / 16) * KDIM;  // 3,145,728
  pack_kernel<<<total / 256, 256, 0, stream>>>(x32, w32, sy, x8f, w8f, tail);

  const int nblocks = (MDIM / BM) * (NDIM / BN);  // 512
  gemm_kernel<<<nblocks, 512, 0, stream>>>(x8f, w8f, sx, sw, sy, out);
}